// Round 2
// baseline (219.222 us; speedup 1.0000x reference)
//
#include <hip/hip_runtime.h>

// ---------------------------------------------------------------------------
// Conv2DQwenRMSNorm: y = x @ W^T, W = mean_l(conv_w); RMSNorm(y)*norm_w.
// B=4,S=4096 -> M=16384; H=1024 (N=K).
//
// R5: R4 skeleton (256 blocks x 512 thr, 8 waves, wave = 2x4 tiles 32x32,
// full-N rows for fused RMSNorm) with K-loop restructured:
//  - consume-then-refill FIFO order: MFMAs read bfr[bb]/af[ab] DIRECTLY,
//    refill happens after -> removes 24 VGPRs of WAR-forced copies
//    (a0,a1,b0..b3), relieving the 256-VGPR cap from launch_bounds(512,2)
//  - s_setprio(1) around the 8-MFMA cluster (barrier-free K loop => waves
//    free-run with role diversity; the regime where setprio pays)
// ---------------------------------------------------------------------------

using bf16x8 = __attribute__((ext_vector_type(8))) short;
using f32x16 = __attribute__((ext_vector_type(16))) float;
using f32x4  = __attribute__((ext_vector_type(4))) float;

#define NDIM 1024
#define MTILE 64

__device__ __forceinline__ unsigned short f2bf(float f) {
    unsigned u = __float_as_uint(f);
    u += 0x7fffu + ((u >> 16) & 1u);          // RNE
    return (unsigned short)(u >> 16);
}

// ---- Kernel 1: W = mean_l conv_w, bf16, fragment-major ---------------------
__global__ __launch_bounds__(256) void wprep_kernel(const float* __restrict__ cw,
                                                    unsigned short* __restrict__ Wf) {
    const int idx = blockIdx.x * 256 + threadIdx.x;  // 0..262143
    const int o   = idx >> 8;                        // row 0..1023
    const int q   = idx & 255;                       // float4 index in row
    const float* p = cw + (size_t)o * NDIM + (q << 2);
    f32x4 s = {0.f, 0.f, 0.f, 0.f};
#pragma unroll
    for (int l = 0; l < 20; ++l) {
        f32x4 v = __builtin_nontemporal_load((const f32x4*)(p + (size_t)l * (NDIM * NDIM)));
        s += v;
    }
    const float sc = 0.05f;                          // 1/L
    ushort4 o4;
    o4.x = f2bf(s[0] * sc); o4.y = f2bf(s[1] * sc);
    o4.z = f2bf(s[2] * sc); o4.w = f2bf(s[3] * sc);
    const int ct  = o >> 5, ml = o & 31;
    const int k16 = q >> 2, h = (q >> 1) & 1, half = q & 1;
    // frag-major: frag(ct,k16)=1KB; slot lane=(h*32+ml) holds W[ct*32+ml][k16*16+h*8..+7]
    *(ushort4*)((char*)Wf + (((ct << 6) + k16) << 10) + (((h << 5) + ml) << 4) + (half << 3)) = o4;
}

// ---- Kernel 2: fused GEMM + RMSNorm ---------------------------------------
__global__ __launch_bounds__(512, 2) void gemm_rms_kernel(
        const float* __restrict__ x, const unsigned short* __restrict__ Wf,
        const float* __restrict__ nw, float* __restrict__ out) {
    __shared__ short lAf[MTILE * NDIM];              // 128 KB, frag-major
    __shared__ float rowss[MTILE];

    const int tid  = threadIdx.x;
    const int wv   = tid >> 6;                       // 0..7
    const int lane = tid & 63;
    const int ml   = lane & 31;
    const int h    = lane >> 5;
    const int row0 = blockIdx.x * MTILE;
    const int phase = (blockIdx.x * 37) & 63;        // L2 decorrelation

    if (tid < MTILE) rowss[tid] = 0.f;

    // ---- stage A panel: 64 rows x 1024 k, fp32->bf16, frag-major + swizzle --
    {
        const int row = tid >> 3;                    // 0..63
        const int rt  = row >> 5, rml = row & 31;
        const float* xr = x + (size_t)(row0 + row) * NDIM;
#pragma unroll
        for (int it = 0; it < 16; ++it) {
            const int k0 = ((tid & 7) << 3) + (it << 6);   // 8-elem chunk base
            f32x4 v0 = __builtin_nontemporal_load((const f32x4*)(xr + k0));
            f32x4 v1 = __builtin_nontemporal_load((const f32x4*)(xr + k0 + 4));
            bf16x8 c;
            c[0] = (short)f2bf(v0[0]); c[1] = (short)f2bf(v0[1]);
            c[2] = (short)f2bf(v0[2]); c[3] = (short)f2bf(v0[3]);
            c[4] = (short)f2bf(v1[0]); c[5] = (short)f2bf(v1[1]);
            c[6] = (short)f2bf(v1[2]); c[7] = (short)f2bf(v1[3]);
            const int k16 = k0 >> 4, hh = (k0 >> 3) & 1;
            const int slot = ((hh << 5) + rml) ^ (k16 & 7);
            *(bf16x8*)((char*)lAf + (((rt << 6) + k16) << 10) + (slot << 4)) = c;
        }
    }
    __syncthreads();

    // ---- K loop: depth-4 B / depth-2 A FIFO, consume-then-refill, no bar ----
    const char* bB[4];
#pragma unroll
    for (int c = 0; c < 4; ++c)
        bB[c] = (const char*)Wf + ((((wv << 2) + c) << 6) << 10) + (lane << 4);

    f32x16 acc[2][4];
#pragma unroll
    for (int tr = 0; tr < 2; ++tr)
#pragma unroll
        for (int tc = 0; tc < 4; ++tc)
#pragma unroll
            for (int r = 0; r < 16; ++r) acc[tr][tc][r] = 0.f;

    bf16x8 af[2][2], bfr[4][4];
#pragma unroll
    for (int d = 0; d < 4; ++d) {
        const int k = (d + phase) & 63;
#pragma unroll
        for (int c = 0; c < 4; ++c)
            bfr[d][c] = *(const bf16x8*)(bB[c] + (k << 10));
    }
#pragma unroll
    for (int d = 0; d < 2; ++d) {
        const int k = (d + phase) & 63;
#pragma unroll
        for (int tr = 0; tr < 2; ++tr)
            af[d][tr] = *(const bf16x8*)((const char*)lAf +
                        (((tr << 6) + k) << 10) + ((lane ^ (k & 7)) << 4));
    }

#pragma unroll 4
    for (int i = 0; i < 64; ++i) {
        const int bb = i & 3, ab = i & 1;
        // consume: MFMAs read FIFO slots directly (no WAR copies)
        __builtin_amdgcn_s_setprio(1);
        acc[0][0] = __builtin_amdgcn_mfma_f32_32x32x16_bf16(af[ab][0], bfr[bb][0], acc[0][0], 0, 0, 0);
        acc[0][1] = __builtin_amdgcn_mfma_f32_32x32x16_bf16(af[ab][0], bfr[bb][1], acc[0][1], 0, 0, 0);
        acc[0][2] = __builtin_amdgcn_mfma_f32_32x32x16_bf16(af[ab][0], bfr[bb][2], acc[0][2], 0, 0, 0);
        acc[0][3] = __builtin_amdgcn_mfma_f32_32x32x16_bf16(af[ab][0], bfr[bb][3], acc[0][3], 0, 0, 0);
        acc[1][0] = __builtin_amdgcn_mfma_f32_32x32x16_bf16(af[ab][1], bfr[bb][0], acc[1][0], 0, 0, 0);
        acc[1][1] = __builtin_amdgcn_mfma_f32_32x32x16_bf16(af[ab][1], bfr[bb][1], acc[1][1], 0, 0, 0);
        acc[1][2] = __builtin_amdgcn_mfma_f32_32x32x16_bf16(af[ab][1], bfr[bb][2], acc[1][2], 0, 0, 0);
        acc[1][3] = __builtin_amdgcn_mfma_f32_32x32x16_bf16(af[ab][1], bfr[bb][3], acc[1][3], 0, 0, 0);
        __builtin_amdgcn_s_setprio(0);
        // refill: slot just consumed gets k for i+4 (B) / i+2 (A)
        if (i + 4 < 64) {
            const int kn = (i + 4 + phase) & 63;
#pragma unroll
            for (int c = 0; c < 4; ++c)
                bfr[bb][c] = *(const bf16x8*)(bB[c] + (kn << 10));
        }
        if (i + 2 < 64) {
            const int kn = (i + 2 + phase) & 63;
#pragma unroll
            for (int tr = 0; tr < 2; ++tr)
                af[ab][tr] = *(const bf16x8*)((const char*)lAf +
                             (((tr << 6) + kn) << 10) + ((lane ^ (kn & 7)) << 4));
        }
    }

    // ---- epilogue: fused RMSNorm ----
    __syncthreads();                                 // rowss init visible
    // C/D layout (32x32): col = lane&31, row = (r&3) + 8*(r>>2) + 4*(lane>>5)
#pragma unroll
    for (int tr = 0; tr < 2; ++tr) {
#pragma unroll
        for (int r = 0; r < 16; ++r) {
            float v = 0.f;
#pragma unroll
            for (int tc = 0; tc < 4; ++tc) { float a = acc[tr][tc][r]; v += a * a; }
#pragma unroll
            for (int m = 1; m <= 16; m <<= 1) v += __shfl_xor(v, m, 64);
            if (ml == 0)
                atomicAdd(&rowss[tr * 32 + (r & 3) + 8 * (r >> 2) + 4 * h], v);
        }
    }
    __syncthreads();
    if (tid < MTILE) rowss[tid] = rsqrtf(rowss[tid] * (1.0f / 1024.0f) + 1e-6f);
    __syncthreads();

    float nwv[4];
#pragma unroll
    for (int tc = 0; tc < 4; ++tc) nwv[tc] = nw[(wv << 7) + tc * 32 + ml];

#pragma unroll
    for (int tr = 0; tr < 2; ++tr) {
#pragma unroll
        for (int r = 0; r < 16; ++r) {
            const int m = tr * 32 + (r & 3) + 8 * (r >> 2) + 4 * h;
            const float rs = rowss[m];
            float* orow = out + (size_t)(row0 + m) * NDIM + (wv << 7) + ml;
#pragma unroll
            for (int tc = 0; tc < 4; ++tc)
                __builtin_nontemporal_store(acc[tr][tc][r] * rs * nwv[tc], orow + tc * 32);
        }
    }
}

extern "C" void kernel_launch(void* const* d_in, const int* in_sizes, int n_in,
                              void* d_out, int out_size, void* d_ws, size_t ws_size,
                              hipStream_t stream) {
    const float* x  = (const float*)d_in[0];
    const float* cw = (const float*)d_in[1];
    const float* nw = (const float*)d_in[2];
    float* out = (float*)d_out;
    unsigned short* Wf = (unsigned short*)d_ws;   // 2 MB fragment-major W

    hipLaunchKernelGGL(wprep_kernel, dim3(1024), dim3(256), 0, stream, cw, Wf);
    hipLaunchKernelGGL(gemm_rms_kernel, dim3(256), dim3(512), 0, stream, x, Wf, nw, out);
}

// Round 3
// 218.999 us; speedup vs baseline: 1.0010x; 1.0010x over previous
//
#include <hip/hip_runtime.h>

// ---------------------------------------------------------------------------
// Conv2DQwenRMSNorm: y = x @ W^T, W = mean_l(conv_w); RMSNorm(y)*norm_w.
// B=4,S=4096 -> M=16384; H=1024 (N=K).
//
// R6: chunked-pipeline rework of the 64 us GEMM dispatch (MfmaUtil 20%,
// VALUBusy 11%, occ 18.8% => phase-serialization, not a BW ceiling):
//  - A panel staged in 4 K-chunks; chunk c+1's global loads issue at
//    section-c top, convert+ds_write at mid-section (T14 async-stage),
//    so the ~10 us HBM stage overlaps the K-loop instead of preceding it
//  - raw lgkmcnt(0)+s_barrier per section (NO vmcnt drain -> B prefetches
//    cross the barrier, T4) + sched_barrier(0) fence (rule 18)
//  - B register FIFO depth 4->2 funds the 32 staging VGPRs (no spill:
//    ~110 arch + 128 acc < 256)
// ---------------------------------------------------------------------------

using bf16x8 = __attribute__((ext_vector_type(8))) short;
using f32x16 = __attribute__((ext_vector_type(16))) float;
using f32x4  = __attribute__((ext_vector_type(4))) float;

#define NDIM 1024
#define MTILE 64

__device__ __forceinline__ unsigned short f2bf(float f) {
    unsigned u = __float_as_uint(f);
    u += 0x7fffu + ((u >> 16) & 1u);          // RNE
    return (unsigned short)(u >> 16);
}

// ---- Kernel 1: W = mean_l conv_w, bf16, fragment-major ---------------------
__global__ __launch_bounds__(256) void wprep_kernel(const float* __restrict__ cw,
                                                    unsigned short* __restrict__ Wf) {
    const int idx = blockIdx.x * 256 + threadIdx.x;  // 0..262143
    const int o   = idx >> 8;                        // row 0..1023
    const int q   = idx & 255;                       // float4 index in row
    const float* p = cw + (size_t)o * NDIM + (q << 2);
    f32x4 s = {0.f, 0.f, 0.f, 0.f};
#pragma unroll
    for (int l = 0; l < 20; ++l) {
        f32x4 v = __builtin_nontemporal_load((const f32x4*)(p + (size_t)l * (NDIM * NDIM)));
        s += v;
    }
    const float sc = 0.05f;                          // 1/L
    ushort4 o4;
    o4.x = f2bf(s[0] * sc); o4.y = f2bf(s[1] * sc);
    o4.z = f2bf(s[2] * sc); o4.w = f2bf(s[3] * sc);
    const int ct  = o >> 5, ml = o & 31;
    const int k16 = q >> 2, h = (q >> 1) & 1, half = q & 1;
    // frag-major: frag(ct,k16)=1KB; slot lane=(h*32+ml) holds W[ct*32+ml][k16*16+h*8..+7]
    *(ushort4*)((char*)Wf + (((ct << 6) + k16) << 10) + (((h << 5) + ml) << 4) + (half << 3)) = o4;
}

// ---- Kernel 2: fused GEMM + RMSNorm ---------------------------------------
__global__ __launch_bounds__(512, 2) void gemm_rms_kernel(
        const float* __restrict__ x, const unsigned short* __restrict__ Wf,
        const float* __restrict__ nw, float* __restrict__ out) {
    __shared__ short lAf[MTILE * NDIM];              // 128 KB, frag-major
    __shared__ float rowss[MTILE];

    const int tid  = threadIdx.x;
    const int wv   = tid >> 6;                       // 0..7
    const int lane = tid & 63;
    const int ml   = lane & 31;
    const int h    = lane >> 5;
    const int row0 = blockIdx.x * MTILE;
    const int phase = (blockIdx.x * 37) & 15;        // per-chunk L2 decorrelation

    if (tid < MTILE) rowss[tid] = 0.f;

    // staging geometry (all 512 threads): row = tid>>3, 8-elem cols by tid&7
    const int row = tid >> 3;                        // 0..63
    const int rt  = row >> 5, rml = row & 31;
    const float* xr = x + (size_t)(row0 + row) * NDIM;
    const int kbase = (tid & 7) << 3;

    // B bases: wave wv owns column-tiles ct = wv*4 .. wv*4+3
    const char* bB[4];
#pragma unroll
    for (int c = 0; c < 4; ++c)
        bB[c] = (const char*)Wf + ((((wv << 2) + c) << 6) << 10) + (lane << 4);

    // ---- warm B FIFO (depth 2) for i = 0,1 — issued before staging so the
    //      L2 loads are deep in flight by the time the K-loop starts
    bf16x8 bfr[2][4];
#pragma unroll
    for (int d = 0; d < 2; ++d) {
        const int k16 = (d + phase) & 15;            // section 0
#pragma unroll
        for (int cc = 0; cc < 4; ++cc)
            bfr[d][cc] = *(const bf16x8*)(bB[cc] + (k16 << 10));
    }

    // ---- prologue: stage chunk 0 only (64 rows x 256 k, fp32->bf16) ----
#pragma unroll
    for (int it = 0; it < 4; ++it) {
        const int k0 = kbase + (it << 6);
        f32x4 v0 = __builtin_nontemporal_load((const f32x4*)(xr + k0));
        f32x4 v1 = __builtin_nontemporal_load((const f32x4*)(xr + k0 + 4));
        bf16x8 c8;
        c8[0] = (short)f2bf(v0[0]); c8[1] = (short)f2bf(v0[1]);
        c8[2] = (short)f2bf(v0[2]); c8[3] = (short)f2bf(v0[3]);
        c8[4] = (short)f2bf(v1[0]); c8[5] = (short)f2bf(v1[1]);
        c8[6] = (short)f2bf(v1[2]); c8[7] = (short)f2bf(v1[3]);
        const int k16 = k0 >> 4, hh = (k0 >> 3) & 1;
        const int slot = ((hh << 5) + rml) ^ (k16 & 7);
        *(bf16x8*)((char*)lAf + (((rt << 6) + k16) << 10) + (slot << 4)) = c8;
    }
    __syncthreads();

    f32x16 acc[2][4];
#pragma unroll
    for (int tr = 0; tr < 2; ++tr)
#pragma unroll
        for (int tc = 0; tc < 4; ++tc)
#pragma unroll
            for (int r = 0; r < 16; ++r) acc[tr][tc][r] = 0.f;

    bf16x8 af[2][2];

    // ---- pipelined K loop: 4 sections x 16 iters; section c computes chunk c
    //      while staging chunk c+1 ----
#pragma unroll
    for (int c = 0; c < 4; ++c) {
        // issue global loads for chunk c+1 ASAP (consumed at j==7)
        f32x4 g0[4], g1[4];
        if (c < 3) {
#pragma unroll
            for (int it = 0; it < 4; ++it) {
                const int k0 = kbase + ((((c + 1) << 2) + it) << 6);
                g0[it] = __builtin_nontemporal_load((const f32x4*)(xr + k0));
                g1[it] = __builtin_nontemporal_load((const f32x4*)(xr + k0 + 4));
            }
        }
        // A warm for j = 0,1 of this section (chunk c is barrier-synced)
#pragma unroll
        for (int d = 0; d < 2; ++d) {
            const int k16 = (c << 4) + ((d + phase) & 15);
#pragma unroll
            for (int tr = 0; tr < 2; ++tr)
                af[d][tr] = *(const bf16x8*)((const char*)lAf +
                            (((tr << 6) + k16) << 10) + ((lane ^ (k16 & 7)) << 4));
        }

#pragma unroll
        for (int j = 0; j < 16; ++j) {
            const int i  = (c << 4) + j;
            const int ab = j & 1, bb = i & 1;
            __builtin_amdgcn_s_setprio(1);
            acc[0][0] = __builtin_amdgcn_mfma_f32_32x32x16_bf16(af[ab][0], bfr[bb][0], acc[0][0], 0, 0, 0);
            acc[0][1] = __builtin_amdgcn_mfma_f32_32x32x16_bf16(af[ab][0], bfr[bb][1], acc[0][1], 0, 0, 0);
            acc[0][2] = __builtin_amdgcn_mfma_f32_32x32x16_bf16(af[ab][0], bfr[bb][2], acc[0][2], 0, 0, 0);
            acc[0][3] = __builtin_amdgcn_mfma_f32_32x32x16_bf16(af[ab][0], bfr[bb][3], acc[0][3], 0, 0, 0);
            acc[1][0] = __builtin_amdgcn_mfma_f32_32x32x16_bf16(af[ab][1], bfr[bb][0], acc[1][0], 0, 0, 0);
            acc[1][1] = __builtin_amdgcn_mfma_f32_32x32x16_bf16(af[ab][1], bfr[bb][1], acc[1][1], 0, 0, 0);
            acc[1][2] = __builtin_amdgcn_mfma_f32_32x32x16_bf16(af[ab][1], bfr[bb][2], acc[1][2], 0, 0, 0);
            acc[1][3] = __builtin_amdgcn_mfma_f32_32x32x16_bf16(af[ab][1], bfr[bb][3], acc[1][3], 0, 0, 0);
            __builtin_amdgcn_s_setprio(0);
            // B refill (consume-then-refill, distance 2, crosses sections)
            if (i + 2 < 64) {
                const int i2 = i + 2;
                const int k16n = (i2 & ~15) + (((i2 & 15) + phase) & 15);
#pragma unroll
                for (int cc = 0; cc < 4; ++cc)
                    bfr[bb][cc] = *(const bf16x8*)(bB[cc] + (k16n << 10));
            }
            // A refill (distance 2, within section only — chunk c is synced)
            if (j + 2 < 16) {
                const int k16n = (c << 4) + (((j + 2) + phase) & 15);
#pragma unroll
                for (int tr = 0; tr < 2; ++tr)
                    af[ab][tr] = *(const bf16x8*)((const char*)lAf +
                                 (((tr << 6) + k16n) << 10) + ((lane ^ (k16n & 7)) << 4));
            }
            // mid-section: convert + ds_write staged chunk c+1
            if (j == 7 && c < 3) {
#pragma unroll
                for (int it = 0; it < 4; ++it) {
                    const int k0 = kbase + ((((c + 1) << 2) + it) << 6);
                    bf16x8 c8;
                    c8[0] = (short)f2bf(g0[it][0]); c8[1] = (short)f2bf(g0[it][1]);
                    c8[2] = (short)f2bf(g0[it][2]); c8[3] = (short)f2bf(g0[it][3]);
                    c8[4] = (short)f2bf(g1[it][0]); c8[5] = (short)f2bf(g1[it][1]);
                    c8[6] = (short)f2bf(g1[it][2]); c8[7] = (short)f2bf(g1[it][3]);
                    const int k16 = k0 >> 4, hh = (k0 >> 3) & 1;
                    const int slot = ((hh << 5) + rml) ^ (k16 & 7);
                    *(bf16x8*)((char*)lAf + (((rt << 6) + k16) << 10) + (slot << 4)) = c8;
                }
            }
        }
        // section barrier: lgkm drain only (B prefetches stay in flight);
        // not needed after the last section (epilogue has its own syncs)
        if (c < 3) {
            asm volatile("s_waitcnt lgkmcnt(0)" ::: "memory");
            __builtin_amdgcn_s_barrier();
            __builtin_amdgcn_sched_barrier(0);
        }
    }

    // ---- epilogue: fused RMSNorm ----
    // C/D layout (32x32): col = lane&31, row = (r&3) + 8*(r>>2) + 4*(lane>>5)
#pragma unroll
    for (int tr = 0; tr < 2; ++tr) {
#pragma unroll
        for (int r = 0; r < 16; ++r) {
            float v = 0.f;
#pragma unroll
            for (int tc = 0; tc < 4; ++tc) { float a = acc[tr][tc][r]; v += a * a; }
#pragma unroll
            for (int m = 1; m <= 16; m <<= 1) v += __shfl_xor(v, m, 64);
            if (ml == 0)
                atomicAdd(&rowss[tr * 32 + (r & 3) + 8 * (r >> 2) + 4 * h], v);
        }
    }
    __syncthreads();
    if (tid < MTILE) rowss[tid] = rsqrtf(rowss[tid] * (1.0f / 1024.0f) + 1e-6f);
    __syncthreads();

    float nwv[4];
#pragma unroll
    for (int tc = 0; tc < 4; ++tc) nwv[tc] = nw[(wv << 7) + tc * 32 + ml];

#pragma unroll
    for (int tr = 0; tr < 2; ++tr) {
#pragma unroll
        for (int r = 0; r < 16; ++r) {
            const int m = tr * 32 + (r & 3) + 8 * (r >> 2) + 4 * h;
            const float rs = rowss[m];
            float* orow = out + (size_t)(row0 + m) * NDIM + (wv << 7) + ml;
#pragma unroll
            for (int tc = 0; tc < 4; ++tc)
                __builtin_nontemporal_store(acc[tr][tc][r] * rs * nwv[tc], orow + tc * 32);
        }
    }
}

extern "C" void kernel_launch(void* const* d_in, const int* in_sizes, int n_in,
                              void* d_out, int out_size, void* d_ws, size_t ws_size,
                              hipStream_t stream) {
    const float* x  = (const float*)d_in[0];
    const float* cw = (const float*)d_in[1];
    const float* nw = (const float*)d_in[2];
    float* out = (float*)d_out;
    unsigned short* Wf = (unsigned short*)d_ws;   // 2 MB fragment-major W

    hipLaunchKernelGGL(wprep_kernel, dim3(1024), dim3(256), 0, stream, cw, Wf);
    hipLaunchKernelGGL(gemm_rms_kernel, dim3(256), dim3(512), 0, stream, x, Wf, nw, out);
}